// Round 2
// baseline (392.484 us; speedup 1.0000x reference)
//
#include <hip/hip_runtime.h>
#include <hip/hip_cooperative_groups.h>
#include <math.h>

namespace cg = cooperative_groups;

#define NN 100000
#define EE 1600000
#define KB 256          // buckets == blocks == CUs
#define RR 391          // ceil(NN / KB); srel < 391 < 2^15, dst < 2^17
#define CAP 8192        // fixed per-bucket capacity (avg 6250, sigma ~76)
#define EPB 6250        // EE / KB exactly
#define EITER 7         // ceil(EPB / 1024)

// Single cooperative kernel: partition -> (deg+nrm+proj) -> agg1 -> agg2 -> edge_out
// Block b owns bucket b (nodes [b*RR, b*RR+RR)) AND edge chunk [b*EPB, (b+1)*EPB).
// Bucket pk, nrm, and the chunk's (s,d) live in LDS across grid.sync()s.
// gcur[] is memset to 0 per launch; cursors are RELATIVE to bucket base (bkt*CAP).

__global__ __launch_bounds__(1024) void k_fused(
    const float* __restrict__ h,
    const float* __restrict__ w_gcn0,
    const float* __restrict__ w_gcn1,
    const float* __restrict__ w_rate0,
    const float* __restrict__ w_rate1,
    const float* __restrict__ w_alpha,
    const int* __restrict__ esrc,
    const int* __restrict__ edst,
    const int* __restrict__ sfake,
    const int* __restrict__ dfake,
    unsigned int* __restrict__ pk,
    int* __restrict__ gcur,
    float4* __restrict__ w4,
    float4* __restrict__ z4,
    float4* __restrict__ p4,
    float* __restrict__ out)
{
    __shared__ unsigned int s_pk[CAP];          // 32 KB  bucket edges (phases 2-4)
    __shared__ int   s_s[EPB];                  // 25 KB  chunk src (phase 1 -> 5)
    __shared__ int   s_d[EPB];                  // 25 KB  chunk dst (phase 1 -> 5)
    __shared__ alignas(16) float sP0[128];      // P columns (phase 0 -> 2)
    __shared__ alignas(16) float sP1[128];
    __shared__ alignas(16) float sP2[128];
    __shared__ int   c[RR];                     // degree counts
    __shared__ float s_nrm[RR];                 // deg^-0.5 (phase 2 -> 3,4)
    __shared__ float s0[RR], s1[RR], s2[RR];    // accumulators (also pmat temps)
    __shared__ int   cnt[KB], base[KB];         // partition histogram

    cg::grid_group grid = cg::this_grid();
    const int b = blockIdx.x;
    const int t = threadIdx.x;

    // ---------- phase 0: P = W0 @ W1 @ [rowsum(w_rate0) | w_rate1 | w_alpha] (per-block, redundant) ----------
    if (t < KB) cnt[t] = 0;
    if (t < 128) {
        float s = 0.f;
        for (int j = 0; j < 128; ++j) s += w_rate0[t * 128 + j];
        s0[t] = s;                    // V0
        s1[t] = w_rate1[t];           // V1
        s2[t] = w_alpha[t];           // V2
    }
    __syncthreads();
    if (t < 128) {
        float q0 = 0.f, q1 = 0.f, q2 = 0.f;
        for (int k = 0; k < 128; ++k) {
            float w = w_gcn1[t * 128 + k];
            q0 += w * s0[k]; q1 += w * s1[k]; q2 += w * s2[k];
        }
        s0[128 + t] = q0; s1[128 + t] = q1; s2[128 + t] = q2;   // Q
    }
    __syncthreads();
    if (t < 128) {
        float p0 = 0.f, p1 = 0.f, p2 = 0.f;
        for (int m = 0; m < 128; ++m) {
            float w = w_gcn0[t * 128 + m];
            p0 += w * s0[128 + m]; p1 += w * s1[128 + m]; p2 += w * s2[128 + m];
        }
        sP0[t] = p0; sP1[t] = p1; sP2[t] = p2;
    }
    __syncthreads();

    // ---------- phase 1: partition my chunk into buckets; stash (s,d) in LDS ----------
    const int e0 = b * EPB;
    unsigned int pkv[EITER];
    int bkt[EITER];
    #pragma unroll
    for (int r = 0; r < EITER; ++r) {
        int i = r * 1024 + t;
        if (i < EPB) {
            int s = esrc[e0 + i];
            int d = edst[e0 + i];
            s_s[i] = s; s_d[i] = d;
            int bb = s / RR;
            bkt[r] = bb;
            pkv[r] = (unsigned int)d | ((unsigned int)(s - bb * RR) << 17);
            atomicAdd(&cnt[bb], 1);
        } else bkt[r] = -1;
    }
    __syncthreads();
    if (t < KB) base[t] = cnt[t] ? atomicAdd(&gcur[t], cnt[t]) : 0;   // RELATIVE cursor
    __syncthreads();
    if (t < KB) cnt[t] = 0;
    __syncthreads();
    #pragma unroll
    for (int r = 0; r < EITER; ++r) {
        if (bkt[r] >= 0) {
            int rr = atomicAdd(&cnt[bkt[r]], 1);
            int rel = base[bkt[r]] + rr;
            if (rel < CAP) pk[bkt[r] * CAP + rel] = pkv[r];   // overflow guard (stat. impossible)
        }
    }
    grid.sync();

    // ---------- phase 2: bucket b: load pk -> LDS, degrees, nrm, w = nrm*(h@P) ----------
    const int P0 = b * CAP;
    int m = gcur[b]; if (m > CAP) m = CAP;
    const int nlo = b * RR;
    const int nn  = (NN - nlo) < RR ? (NN - nlo) : RR;
    if (t < RR) c[t] = 0;
    __syncthreads();
    for (int i = t; i < m; i += 1024) {
        unsigned int w = pk[P0 + i];
        s_pk[i] = w;
        atomicAdd(&c[w >> 17], 1);
    }
    __syncthreads();
    if (t < nn) s_nrm[t] = rsqrtf((float)c[t]);
    __syncthreads();
    {
        const int hw  = t >> 5;        // half-wave 0..31
        const int l32 = t & 31;
        const int c4  = l32 * 4;
        float4 c0 = *(const float4*)(sP0 + c4);
        float4 c1 = *(const float4*)(sP1 + c4);
        float4 c2 = *(const float4*)(sP2 + c4);
        for (int i0 = 0; i0 < nn; i0 += 32) {
            int i = i0 + hw;
            if (i >= nn) break;
            int node = nlo + i;
            float4 hv = *(const float4*)(h + (size_t)node * 128 + c4);
            float p0v = hv.x * c0.x + hv.y * c0.y + hv.z * c0.z + hv.w * c0.w;
            float p1v = hv.x * c1.x + hv.y * c1.y + hv.z * c1.z + hv.w * c1.w;
            float p2v = hv.x * c2.x + hv.y * c2.y + hv.z * c2.z + hv.w * c2.w;
            #pragma unroll
            for (int off = 16; off > 0; off >>= 1) {
                p0v += __shfl_down(p0v, off, 32);
                p1v += __shfl_down(p1v, off, 32);
                p2v += __shfl_down(p2v, off, 32);
            }
            if (l32 == 0) {
                float nv = s_nrm[i];
                w4[node] = make_float4(nv * p0v, nv * p1v, nv * p2v, 0.f);
            }
        }
    }
    grid.sync();

    // ---------- phase 3: z = nrm^2 * (A w)   (pk from LDS) ----------
    if (t < RR) { s0[t] = 0.f; s1[t] = 0.f; s2[t] = 0.f; }
    __syncthreads();
    for (int i = t; i < m; i += 1024) {
        unsigned int w = s_pk[i];
        float4 v = w4[w & 0x1FFFFu];
        int srel = (int)(w >> 17);
        atomicAdd(&s0[srel], v.x);
        atomicAdd(&s1[srel], v.y);
        atomicAdd(&s2[srel], v.z);
    }
    __syncthreads();
    if (t < nn) {
        float nv = s_nrm[t], sc = nv * nv;
        z4[nlo + t] = make_float4(sc * s0[t], sc * s1[t], sc * s2[t], 0.f);
    }
    grid.sync();

    // ---------- phase 4: p = nrm * (A z) ----------
    if (t < RR) { s0[t] = 0.f; s1[t] = 0.f; s2[t] = 0.f; }
    __syncthreads();
    for (int i = t; i < m; i += 1024) {
        unsigned int w = s_pk[i];
        float4 v = z4[w & 0x1FFFFu];
        int srel = (int)(w >> 17);
        atomicAdd(&s0[srel], v.x);
        atomicAdd(&s1[srel], v.y);
        atomicAdd(&s2[srel], v.z);
    }
    __syncthreads();
    if (t < nn) {
        float nv = s_nrm[t];
        p4[nlo + t] = make_float4(nv * s0[t], nv * s1[t], nv * s2[t], 0.f);
    }
    grid.sync();

    // ---------- phase 5: edge outputs for my chunk ((s,d) from LDS) ----------
    #pragma unroll
    for (int r = 0; r < EITER; ++r) {
        int i = r * 1024 + t;
        if (i < EPB) {
            int e = e0 + i;
            int s = s_s[i], d = s_d[i];
            int sf = sfake[e]; sf = sf < 0 ? 0 : (sf >= NN ? NN - 1 : sf);
            int df = dfake[e]; df = df < 0 ? 0 : (df >= NN ? NN - 1 : df);
            float4 ps = p4[s], pd = p4[d], psf = p4[sf], pdf = p4[df];
            out[e]                  = expf(ps.x + pd.x);
            out[(size_t)EE + e]     = expf(ps.y + pd.y);
            out[(size_t)2 * EE + e] = 1.f / (1.f + expf(-(ps.z * pd.z)));
            out[(size_t)3 * EE + e] = expf(psf.x + 128.f * pdf.y);
            out[(size_t)4 * EE + e] = expf(psf.y + pdf.y);
            out[(size_t)5 * EE + e] = 1.f / (1.f + expf(-(ps.z * pdf.z)));
        }
    }
}

// ---------------- launch ----------------

extern "C" void kernel_launch(void* const* d_in, const int* in_sizes, int n_in,
                              void* d_out, int out_size, void* d_ws, size_t ws_size,
                              hipStream_t stream) {
    const float* h       = (const float*)d_in[0];
    const float* w_gcn0  = (const float*)d_in[1];
    const float* w_gcn1  = (const float*)d_in[2];
    const float* w_rate0 = (const float*)d_in[3];
    const float* w_rate1 = (const float*)d_in[4];
    const float* w_alpha = (const float*)d_in[5];
    const int* edge_src  = (const int*)d_in[6];
    const int* edge_dst  = (const int*)d_in[7];
    const int* src_fake  = (const int*)d_in[8];
    const int* dst_fake  = (const int*)d_in[9];
    float* out = (float*)d_out;

    char* p = (char*)d_ws;
    auto alloc = [&](size_t bytes) {
        char* r = p;
        p += (bytes + 255) & ~(size_t)255;
        return r;
    };
    unsigned int* pk = (unsigned int*)alloc((size_t)KB * CAP * 4);   // 8.4 MB
    int* gcur   = (int*)alloc(KB * 4);
    float4* w4  = (float4*)alloc((size_t)NN * 16);
    float4* z4  = (float4*)alloc((size_t)NN * 16);
    float4* p4  = (float4*)alloc((size_t)NN * 16);

    hipMemsetAsync(gcur, 0, KB * sizeof(int), stream);

    void* args[] = { &h, &w_gcn0, &w_gcn1, &w_rate0, &w_rate1, &w_alpha,
                     &edge_src, &edge_dst, &src_fake, &dst_fake,
                     &pk, &gcur, &w4, &z4, &p4, &out };
    hipLaunchCooperativeKernel((void*)k_fused, dim3(KB), dim3(1024), args, 0, stream);
}

// Round 3
// 296.179 us; speedup vs baseline: 1.3252x; 1.3252x over previous
//
#include <hip/hip_runtime.h>
#include <math.h>

#define NN 100000
#define EE 1600000
#define KB 256          // buckets
#define RR 391          // ceil(NN / KB); srel < 391, dst < 2^17
#define CAP 8192        // per-bucket capacity (avg 6250, sigma ~76)

// ---------------- P = W0 @ W1 @ [rowsum(w_rate0) | w_rate1 | w_alpha]  (128x3) ----------------
// 1024 threads; 8 lanes per row (seg = t&7 covers 16 consecutive floats) -> coalesced loads.

__global__ __launch_bounds__(1024) void k_pmat(const float* __restrict__ w_gcn0,
                                               const float* __restrict__ w_gcn1,
                                               const float* __restrict__ w_rate0,
                                               const float* __restrict__ w_rate1,
                                               const float* __restrict__ w_alpha,
                                               float* __restrict__ Pt0, float* __restrict__ Pt1,
                                               float* __restrict__ Pt2) {
    __shared__ float V0[128], V1[128], V2[128];
    __shared__ float Q0[128], Q1[128], Q2[128];
    int t = threadIdx.x;
    int r = t >> 3, seg = t & 7;
    {   // V0 = rowsum(w_rate0)
        const float* p = w_rate0 + r * 128 + seg * 16;
        float s = 0.f;
        #pragma unroll
        for (int k = 0; k < 16; ++k) s += p[k];
        s += __shfl_down(s, 4, 8); s += __shfl_down(s, 2, 8); s += __shfl_down(s, 1, 8);
        if (seg == 0) V0[r] = s;
    }
    if (t < 128) { V1[t] = w_rate1[t]; V2[t] = w_alpha[t]; }
    __syncthreads();
    {   // Q = w_gcn1 @ V
        const float* p = w_gcn1 + r * 128 + seg * 16;
        float q0 = 0.f, q1 = 0.f, q2 = 0.f;
        #pragma unroll
        for (int k = 0; k < 16; ++k) {
            float w = p[k]; int j = seg * 16 + k;
            q0 += w * V0[j]; q1 += w * V1[j]; q2 += w * V2[j];
        }
        q0 += __shfl_down(q0, 4, 8); q0 += __shfl_down(q0, 2, 8); q0 += __shfl_down(q0, 1, 8);
        q1 += __shfl_down(q1, 4, 8); q1 += __shfl_down(q1, 2, 8); q1 += __shfl_down(q1, 1, 8);
        q2 += __shfl_down(q2, 4, 8); q2 += __shfl_down(q2, 2, 8); q2 += __shfl_down(q2, 1, 8);
        if (seg == 0) { Q0[r] = q0; Q1[r] = q1; Q2[r] = q2; }
    }
    __syncthreads();
    {   // P = w_gcn0 @ Q
        const float* p = w_gcn0 + r * 128 + seg * 16;
        float q0 = 0.f, q1 = 0.f, q2 = 0.f;
        #pragma unroll
        for (int k = 0; k < 16; ++k) {
            float w = p[k]; int j = seg * 16 + k;
            q0 += w * Q0[j]; q1 += w * Q1[j]; q2 += w * Q2[j];
        }
        q0 += __shfl_down(q0, 4, 8); q0 += __shfl_down(q0, 2, 8); q0 += __shfl_down(q0, 1, 8);
        q1 += __shfl_down(q1, 4, 8); q1 += __shfl_down(q1, 2, 8); q1 += __shfl_down(q1, 1, 8);
        q2 += __shfl_down(q2, 4, 8); q2 += __shfl_down(q2, 2, 8); q2 += __shfl_down(q2, 1, 8);
        if (seg == 0) { Pt0[r] = q0; Pt1[r] = q1; Pt2[r] = q2; }
    }
}

// ---------------- partition edges into buckets (pk = dst | srel<<17); deg[src]++ via global atomics ----------------

__global__ __launch_bounds__(256) void k_part(const int* __restrict__ src, const int* __restrict__ dst,
                                              int* __restrict__ gcur, int* __restrict__ deg,
                                              unsigned int* __restrict__ pk, int E) {
    __shared__ int cnt[KB];
    __shared__ int base[KB];
    int t = threadIdx.x;
    int e0 = blockIdx.x * 4096;
    cnt[t] = 0;
    __syncthreads();
    unsigned int pkv[16];
    int bkt[16];
    #pragma unroll
    for (int i = 0; i < 16; ++i) {
        int e = e0 + i * 256 + t;
        if (e < E) {
            int s = src[e];
            int d = dst[e];
            int b = s / RR;
            bkt[i] = b;
            pkv[i] = (unsigned int)d | ((unsigned int)(s - b * RR) << 17);
            atomicAdd(&cnt[b], 1);
            atomicAdd(&deg[s], 1);
        } else bkt[i] = -1;
    }
    __syncthreads();
    base[t] = cnt[t] ? atomicAdd(&gcur[t], cnt[t]) : 0;   // relative cursor (gcur memset to 0)
    __syncthreads();
    cnt[t] = 0;
    __syncthreads();
    #pragma unroll
    for (int i = 0; i < 16; ++i) {
        if (bkt[i] >= 0) {
            int rr = atomicAdd(&cnt[bkt[i]], 1);
            int rel = base[bkt[i]] + rr;
            if (rel < CAP) pk[bkt[i] * CAP + rel] = pkv[i];   // overflow guard (stat. impossible)
        }
    }
}

// ---------------- proj: nrm from deg; w4 = nrm*(h@P); prefill z4=(0,0,0,nrm^2), p4=(0,0,0,nrm) ----------------
// 782 blocks x 256 threads; 128 nodes/block; half-wave (32 lanes) per node.

__global__ __launch_bounds__(256) void k_proj(const int* __restrict__ deg, const float* __restrict__ h,
                                              const float* __restrict__ Pt0, const float* __restrict__ Pt1,
                                              const float* __restrict__ Pt2,
                                              float4* __restrict__ w4, float4* __restrict__ z4,
                                              float4* __restrict__ p4) {
    __shared__ float sP0[128], sP1[128], sP2[128], snrm[128];
    int t = threadIdx.x;
    int nlo = blockIdx.x * 128;
    if (t < 128) {
        sP0[t] = Pt0[t]; sP1[t] = Pt1[t]; sP2[t] = Pt2[t];
        int node = nlo + t;
        if (node < NN) {
            float nv = rsqrtf((float)deg[node]);
            snrm[t] = nv;
            z4[node] = make_float4(0.f, 0.f, 0.f, nv * nv);
            p4[node] = make_float4(0.f, 0.f, 0.f, nv);
        }
    }
    __syncthreads();
    int hw = t >> 5;       // 0..7
    int l32 = t & 31;
    int c4 = l32 * 4;
    float4 c0 = *(const float4*)(sP0 + c4);
    float4 c1 = *(const float4*)(sP1 + c4);
    float4 c2 = *(const float4*)(sP2 + c4);
    #pragma unroll 4
    for (int i0 = 0; i0 < 128; i0 += 8) {
        int i = i0 + hw;
        int node = nlo + i;
        if (node < NN) {
            float4 hv = *(const float4*)(h + (size_t)node * 128 + c4);
            float p0v = hv.x * c0.x + hv.y * c0.y + hv.z * c0.z + hv.w * c0.w;
            float p1v = hv.x * c1.x + hv.y * c1.y + hv.z * c1.z + hv.w * c1.w;
            float p2v = hv.x * c2.x + hv.y * c2.y + hv.z * c2.z + hv.w * c2.w;
            #pragma unroll
            for (int off = 16; off > 0; off >>= 1) {
                p0v += __shfl_down(p0v, off, 32);
                p1v += __shfl_down(p1v, off, 32);
                p2v += __shfl_down(p2v, off, 32);
            }
            if (l32 == 0) {
                float nv = snrm[i];
                w4[node] = make_float4(nv * p0v, nv * p1v, nv * p2v, 0.f);
            }
        }
    }
}

// ---------------- agg: pure accumulate into outv.xyz; 2 blocks per bucket; global-atomic combine ----------------
// MODE 1: gather T[dst].xyz as-is (T=w4, already nrm-scaled).
// MODE 2: gather T[dst].xyz * T[dst].w (T=z4, .w = nrm^2).

template<int MODE>
__global__ __launch_bounds__(512) void k_agg(const unsigned int* __restrict__ pk,
                                             const int* __restrict__ gcur,
                                             const float4* __restrict__ T,
                                             float4* __restrict__ outv) {
    __shared__ float s0[RR], s1[RR], s2[RR];
    int b = blockIdx.x >> 1;
    int half = blockIdx.x & 1;
    int t = threadIdx.x;
    if (t < RR) { s0[t] = 0.f; s1[t] = 0.f; s2[t] = 0.f; }
    __syncthreads();
    int m = gcur[b]; if (m > CAP) m = CAP;
    int mh = m >> 1;
    int lo = half ? mh : 0;
    int hi = half ? m : mh;
    const unsigned int* P = pk + b * CAP;
    for (int i = lo + t; i < hi; i += 512) {
        unsigned int w = P[i];
        float4 v = T[w & 0x1FFFFu];
        float x = v.x, y = v.y, z = v.z;
        if (MODE == 2) { x *= v.w; y *= v.w; z *= v.w; }
        int srel = (int)(w >> 17);
        atomicAdd(&s0[srel], x);
        atomicAdd(&s1[srel], y);
        atomicAdd(&s2[srel], z);
    }
    __syncthreads();
    int nlo = b * RR;
    int nn = NN - nlo; if (nn > RR) nn = RR;
    for (int i = t; i < nn; i += 512) {
        float* o = (float*)&outv[nlo + i];
        atomicAdd(o + 0, s0[i]);
        atomicAdd(o + 1, s1[i]);
        atomicAdd(o + 2, s2[i]);
    }
}

// ---------------- edge outputs; p value = p4.w * p4.{x,y,z}; 2 edges/thread for MLP ----------------

__global__ __launch_bounds__(256) void k_edge(const int* __restrict__ esrc, const int* __restrict__ edst,
                                              const int* __restrict__ sfake, const int* __restrict__ dfake,
                                              const float4* __restrict__ p4, float* __restrict__ out, int E) {
    int t = threadIdx.x;
    int e00 = blockIdx.x * 512 + t;
    #pragma unroll
    for (int k = 0; k < 2; ++k) {
        int e = e00 + k * 256;
        if (e < E) {
            int s = esrc[e], d = edst[e];
            int sf = sfake[e]; sf = sf < 0 ? 0 : (sf >= NN ? NN - 1 : sf);
            int df = dfake[e]; df = df < 0 ? 0 : (df >= NN ? NN - 1 : df);
            float4 ps = p4[s], pd = p4[d], psf = p4[sf], pdf = p4[df];
            float psx = ps.w * ps.x, psy = ps.w * ps.y, psz = ps.w * ps.z;
            float pdx = pd.w * pd.x, pdy = pd.w * pd.y, pdz = pd.w * pd.z;
            float sfx = psf.w * psf.x, sfy = psf.w * psf.y;
            float dfy = pdf.w * pdf.y, dfz = pdf.w * pdf.z;
            out[e]                  = expf(psx + pdx);
            out[(size_t)EE + e]     = expf(psy + pdy);
            out[(size_t)2 * EE + e] = 1.f / (1.f + expf(-(psz * pdz)));
            out[(size_t)3 * EE + e] = expf(sfx + 128.f * dfy);
            out[(size_t)4 * EE + e] = expf(sfy + dfy);
            out[(size_t)5 * EE + e] = 1.f / (1.f + expf(-(psz * dfz)));
        }
    }
}

// ---------------- launch ----------------

extern "C" void kernel_launch(void* const* d_in, const int* in_sizes, int n_in,
                              void* d_out, int out_size, void* d_ws, size_t ws_size,
                              hipStream_t stream) {
    const float* h       = (const float*)d_in[0];
    const float* w_gcn0  = (const float*)d_in[1];
    const float* w_gcn1  = (const float*)d_in[2];
    const float* w_rate0 = (const float*)d_in[3];
    const float* w_rate1 = (const float*)d_in[4];
    const float* w_alpha = (const float*)d_in[5];
    const int* edge_src  = (const int*)d_in[6];
    const int* edge_dst  = (const int*)d_in[7];
    const int* src_fake  = (const int*)d_in[8];
    const int* dst_fake  = (const int*)d_in[9];
    float* out = (float*)d_out;

    const int E = EE;

    char* p = (char*)d_ws;
    auto alloc = [&](size_t bytes) {
        char* r = p;
        p += (bytes + 255) & ~(size_t)255;
        return r;
    };
    unsigned int* pk = (unsigned int*)alloc((size_t)KB * CAP * 4);   // 8.4 MB
    int* ctrl   = (int*)alloc((size_t)(KB + NN) * 4);                // gcur | deg
    int* gcur   = ctrl;
    int* deg    = ctrl + KB;
    float4* w4  = (float4*)alloc((size_t)NN * 16);
    float4* z4  = (float4*)alloc((size_t)NN * 16);
    float4* p4  = (float4*)alloc((size_t)NN * 16);
    float* Pt0  = (float*)alloc(512);
    float* Pt1  = (float*)alloc(512);
    float* Pt2  = (float*)alloc(512);

    hipMemsetAsync(ctrl, 0, (size_t)(KB + NN) * 4, stream);

    k_pmat<<<1, 1024, 0, stream>>>(w_gcn0, w_gcn1, w_rate0, w_rate1, w_alpha, Pt0, Pt1, Pt2);
    k_part<<<(E + 4095) / 4096, 256, 0, stream>>>(edge_src, edge_dst, gcur, deg, pk, E);
    k_proj<<<(NN + 127) / 128, 256, 0, stream>>>(deg, h, Pt0, Pt1, Pt2, w4, z4, p4);
    k_agg<1><<<2 * KB, 512, 0, stream>>>(pk, gcur, w4, z4);
    k_agg<2><<<2 * KB, 512, 0, stream>>>(pk, gcur, z4, p4);
    k_edge<<<(E + 511) / 512, 256, 0, stream>>>(edge_src, edge_dst, src_fake, dst_fake, p4, out, E);
}

// Round 4
// 235.790 us; speedup vs baseline: 1.6646x; 1.2561x over previous
//
#include <hip/hip_runtime.h>
#include <math.h>

#define NN 100000
#define EE 1600000
#define KB 256          // buckets
#define RR 391          // ceil(NN / KB); srel < 391, dst < 2^17
#define CAP 8192        // per-bucket capacity (avg 6250, sigma ~76)

// ---------------- P = W0 @ W1 @ [rowsum(w_rate0) | w_rate1 | w_alpha]  (128x3); also zero gcur ----------------
// 1024 threads; 8 lanes per row (seg covers 16 consecutive floats) -> coalesced loads.

__global__ __launch_bounds__(1024) void k_pmat(const float* __restrict__ w_gcn0,
                                               const float* __restrict__ w_gcn1,
                                               const float* __restrict__ w_rate0,
                                               const float* __restrict__ w_rate1,
                                               const float* __restrict__ w_alpha,
                                               float* __restrict__ Pt0, float* __restrict__ Pt1,
                                               float* __restrict__ Pt2, int* __restrict__ gcur) {
    __shared__ float V0[128], V1[128], V2[128];
    __shared__ float Q0[128], Q1[128], Q2[128];
    int t = threadIdx.x;
    if (t < KB) gcur[t] = 0;
    int r = t >> 3, seg = t & 7;
    {   // V0 = rowsum(w_rate0)
        const float* p = w_rate0 + r * 128 + seg * 16;
        float s = 0.f;
        #pragma unroll
        for (int k = 0; k < 16; ++k) s += p[k];
        s += __shfl_down(s, 4, 8); s += __shfl_down(s, 2, 8); s += __shfl_down(s, 1, 8);
        if (seg == 0) V0[r] = s;
    }
    if (t < 128) { V1[t] = w_rate1[t]; V2[t] = w_alpha[t]; }
    __syncthreads();
    {   // Q = w_gcn1 @ V
        const float* p = w_gcn1 + r * 128 + seg * 16;
        float q0 = 0.f, q1 = 0.f, q2 = 0.f;
        #pragma unroll
        for (int k = 0; k < 16; ++k) {
            float w = p[k]; int j = seg * 16 + k;
            q0 += w * V0[j]; q1 += w * V1[j]; q2 += w * V2[j];
        }
        q0 += __shfl_down(q0, 4, 8); q0 += __shfl_down(q0, 2, 8); q0 += __shfl_down(q0, 1, 8);
        q1 += __shfl_down(q1, 4, 8); q1 += __shfl_down(q1, 2, 8); q1 += __shfl_down(q1, 1, 8);
        q2 += __shfl_down(q2, 4, 8); q2 += __shfl_down(q2, 2, 8); q2 += __shfl_down(q2, 1, 8);
        if (seg == 0) { Q0[r] = q0; Q1[r] = q1; Q2[r] = q2; }
    }
    __syncthreads();
    {   // P = w_gcn0 @ Q
        const float* p = w_gcn0 + r * 128 + seg * 16;
        float q0 = 0.f, q1 = 0.f, q2 = 0.f;
        #pragma unroll
        for (int k = 0; k < 16; ++k) {
            float w = p[k]; int j = seg * 16 + k;
            q0 += w * Q0[j]; q1 += w * Q1[j]; q2 += w * Q2[j];
        }
        q0 += __shfl_down(q0, 4, 8); q0 += __shfl_down(q0, 2, 8); q0 += __shfl_down(q0, 1, 8);
        q1 += __shfl_down(q1, 4, 8); q1 += __shfl_down(q1, 2, 8); q1 += __shfl_down(q1, 1, 8);
        q2 += __shfl_down(q2, 4, 8); q2 += __shfl_down(q2, 2, 8); q2 += __shfl_down(q2, 1, 8);
        if (seg == 0) { Pt0[r] = q0; Pt1[r] = q1; Pt2[r] = q2; }
    }
}

// ---------------- partition edges into buckets (pk = dst | srel<<17); NO global atomics on deg ----------------
// 782 blocks x 256 threads x 8 edges/thread.

__global__ __launch_bounds__(256) void k_part(const int* __restrict__ src, const int* __restrict__ dst,
                                              int* __restrict__ gcur, unsigned int* __restrict__ pk, int E) {
    __shared__ int cnt[KB];
    __shared__ int base[KB];
    int t = threadIdx.x;
    int e0 = blockIdx.x * 2048;
    cnt[t] = 0;
    __syncthreads();
    unsigned int pkv[8];
    int bkt[8];
    #pragma unroll
    for (int i = 0; i < 8; ++i) {
        int e = e0 + i * 256 + t;
        if (e < E) {
            int s = src[e];
            int d = dst[e];
            int b = s / RR;
            bkt[i] = b;
            pkv[i] = (unsigned int)d | ((unsigned int)(s - b * RR) << 17);
            atomicAdd(&cnt[b], 1);
        } else bkt[i] = -1;
    }
    __syncthreads();
    base[t] = cnt[t] ? atomicAdd(&gcur[t], cnt[t]) : 0;   // relative cursor (gcur zeroed by k_pmat)
    __syncthreads();
    cnt[t] = 0;
    __syncthreads();
    #pragma unroll
    for (int i = 0; i < 8; ++i) {
        if (bkt[i] >= 0) {
            int rr = atomicAdd(&cnt[bkt[i]], 1);
            int rel = base[bkt[i]] + rr;
            if (rel < CAP) pk[bkt[i] * CAP + rel] = pkv[i];   // overflow guard (stat. impossible)
        }
    }
}

// ---------------- fused per-bucket: degree count (LDS) -> nrm; then w4 = nrm * (h @ P) ----------------
// one block per bucket, 1024 threads; half-wave (32 lanes) per node for the projection.

__global__ __launch_bounds__(1024) void k_cnt_proj(const unsigned int* __restrict__ pk,
                                                   const int* __restrict__ gcur,
                                                   const float* __restrict__ h,
                                                   const float* __restrict__ Pt0, const float* __restrict__ Pt1,
                                                   const float* __restrict__ Pt2,
                                                   float* __restrict__ nrm, float4* __restrict__ w4) {
    __shared__ int c[RR];
    __shared__ float s_nrm[RR];
    __shared__ float sP0[128], sP1[128], sP2[128];
    int b = blockIdx.x;
    int t = threadIdx.x;
    int nlo = b * RR;
    int nn = NN - nlo; if (nn > RR) nn = RR;
    if (nn <= 0) return;
    if (t < 128) { sP0[t] = Pt0[t]; sP1[t] = Pt1[t]; sP2[t] = Pt2[t]; }
    if (t < RR) c[t] = 0;
    __syncthreads();
    int P0 = b * CAP;
    int m = gcur[b]; if (m > CAP) m = CAP;
    for (int i = t; i < m; i += 1024) atomicAdd(&c[pk[P0 + i] >> 17], 1);
    __syncthreads();
    if (t < nn) {
        float nv = rsqrtf((float)c[t]);
        s_nrm[t] = nv;
        nrm[nlo + t] = nv;
    }
    __syncthreads();
    int hw = t >> 5;           // 0..31
    int l32 = t & 31;
    int c4 = l32 * 4;
    float4 c0 = *(const float4*)(sP0 + c4);
    float4 c1 = *(const float4*)(sP1 + c4);
    float4 c2 = *(const float4*)(sP2 + c4);
    for (int i0 = 0; i0 < nn; i0 += 32) {
        int i = i0 + hw;
        if (i >= nn) break;
        int node = nlo + i;
        float4 hv = *(const float4*)(h + (size_t)node * 128 + c4);
        float p0v = hv.x * c0.x + hv.y * c0.y + hv.z * c0.z + hv.w * c0.w;
        float p1v = hv.x * c1.x + hv.y * c1.y + hv.z * c1.z + hv.w * c1.w;
        float p2v = hv.x * c2.x + hv.y * c2.y + hv.z * c2.z + hv.w * c2.w;
        #pragma unroll
        for (int off = 16; off > 0; off >>= 1) {
            p0v += __shfl_down(p0v, off, 32);
            p1v += __shfl_down(p1v, off, 32);
            p2v += __shfl_down(p2v, off, 32);
        }
        if (l32 == 0) {
            float nv = s_nrm[i];
            w4[node] = make_float4(nv * p0v, nv * p1v, nv * p2v, 0.f);
        }
    }
}

// ---------------- bucketed aggregation: 1 block/bucket, LDS accumulate, plain float4 stores ----------------
// mode 1: out[node] = nrm^2 * acc (z);  mode 2: out[node] = nrm * acc (final p)

template<int MODE>
__global__ __launch_bounds__(1024) void k_agg(const unsigned int* __restrict__ pk,
                                              const int* __restrict__ gcur,
                                              const float4* __restrict__ T, const float* __restrict__ nrm,
                                              float4* __restrict__ outv) {
    __shared__ float s0[RR], s1[RR], s2[RR];
    int b = blockIdx.x;
    int t = threadIdx.x;
    int nlo = b * RR;
    int nn = NN - nlo; if (nn > RR) nn = RR;
    if (nn <= 0) return;
    if (t < RR) { s0[t] = 0.f; s1[t] = 0.f; s2[t] = 0.f; }
    __syncthreads();
    int P0 = b * CAP;
    int m = gcur[b]; if (m > CAP) m = CAP;
    for (int i = t; i < m; i += 1024) {
        unsigned int w = pk[P0 + i];
        float4 v = T[w & 0x1FFFFu];
        int srel = (int)(w >> 17);
        atomicAdd(&s0[srel], v.x);
        atomicAdd(&s1[srel], v.y);
        atomicAdd(&s2[srel], v.z);
    }
    __syncthreads();
    for (int i = t; i < nn; i += 1024) {
        int node = nlo + i;
        float nv = nrm[node];
        float sc = (MODE == 1) ? nv * nv : nv;
        outv[node] = make_float4(sc * s0[i], sc * s1[i], sc * s2[i], 0.f);
    }
}

// ---------------- edge outputs (p4 = [r0s, r1v, av, 0] per node); 2 edges/thread ----------------

__global__ __launch_bounds__(256) void k_edge(const int* __restrict__ esrc, const int* __restrict__ edst,
                                              const int* __restrict__ sfake, const int* __restrict__ dfake,
                                              const float4* __restrict__ p4, float* __restrict__ out, int E) {
    int t = threadIdx.x;
    int e00 = blockIdx.x * 512 + t;
    #pragma unroll
    for (int k = 0; k < 2; ++k) {
        int e = e00 + k * 256;
        if (e < E) {
            int s = esrc[e], d = edst[e];
            int sf = sfake[e]; sf = sf < 0 ? 0 : (sf >= NN ? NN - 1 : sf);
            int df = dfake[e]; df = df < 0 ? 0 : (df >= NN ? NN - 1 : df);
            float4 ps = p4[s], pd = p4[d], psf = p4[sf], pdf = p4[df];
            out[e]                  = expf(ps.x + pd.x);
            out[(size_t)EE + e]     = expf(ps.y + pd.y);
            out[(size_t)2 * EE + e] = 1.f / (1.f + expf(-(ps.z * pd.z)));
            out[(size_t)3 * EE + e] = expf(psf.x + 128.f * pdf.y);
            out[(size_t)4 * EE + e] = expf(psf.y + pdf.y);
            out[(size_t)5 * EE + e] = 1.f / (1.f + expf(-(ps.z * pdf.z)));
        }
    }
}

// ---------------- launch ----------------

extern "C" void kernel_launch(void* const* d_in, const int* in_sizes, int n_in,
                              void* d_out, int out_size, void* d_ws, size_t ws_size,
                              hipStream_t stream) {
    const float* h       = (const float*)d_in[0];
    const float* w_gcn0  = (const float*)d_in[1];
    const float* w_gcn1  = (const float*)d_in[2];
    const float* w_rate0 = (const float*)d_in[3];
    const float* w_rate1 = (const float*)d_in[4];
    const float* w_alpha = (const float*)d_in[5];
    const int* edge_src  = (const int*)d_in[6];
    const int* edge_dst  = (const int*)d_in[7];
    const int* src_fake  = (const int*)d_in[8];
    const int* dst_fake  = (const int*)d_in[9];
    float* out = (float*)d_out;

    const int E = EE;

    char* p = (char*)d_ws;
    auto alloc = [&](size_t bytes) {
        char* r = p;
        p += (bytes + 255) & ~(size_t)255;
        return r;
    };
    unsigned int* pk = (unsigned int*)alloc((size_t)KB * CAP * 4);   // 8.4 MB
    int* gcur   = (int*)alloc(KB * 4);
    float* nrm  = (float*)alloc((size_t)NN * 4);
    float4* w4  = (float4*)alloc((size_t)NN * 16);
    float4* z4  = (float4*)alloc((size_t)NN * 16);
    float4* p4  = (float4*)alloc((size_t)NN * 16);
    float* Pt0  = (float*)alloc(512);
    float* Pt1  = (float*)alloc(512);
    float* Pt2  = (float*)alloc(512);

    k_pmat<<<1, 1024, 0, stream>>>(w_gcn0, w_gcn1, w_rate0, w_rate1, w_alpha, Pt0, Pt1, Pt2, gcur);
    k_part<<<(E + 2047) / 2048, 256, 0, stream>>>(edge_src, edge_dst, gcur, pk, E);
    k_cnt_proj<<<KB, 1024, 0, stream>>>(pk, gcur, h, Pt0, Pt1, Pt2, nrm, w4);
    k_agg<1><<<KB, 1024, 0, stream>>>(pk, gcur, w4, nrm, z4);
    k_agg<2><<<KB, 1024, 0, stream>>>(pk, gcur, z4, nrm, p4);
    k_edge<<<(E + 511) / 512, 256, 0, stream>>>(edge_src, edge_dst, src_fake, dst_fake, p4, out, E);
}

// Round 5
// 222.891 us; speedup vs baseline: 1.7609x; 1.0579x over previous
//
#include <hip/hip_runtime.h>
#include <math.h>

#define NN 100000
#define EE 1600000
#define KB 256          // buckets
#define RR 391          // ceil(NN / KB); srel < 391, dst < 2^17
#define CAP 8192        // per-bucket capacity (avg 6250, sigma ~76)

// ---------------- P = W0 @ W1 @ [rowsum(w_rate0) | w_rate1 | w_alpha]  (128x3); also zero gcur ----------------

__global__ __launch_bounds__(1024) void k_pmat(const float* __restrict__ w_gcn0,
                                               const float* __restrict__ w_gcn1,
                                               const float* __restrict__ w_rate0,
                                               const float* __restrict__ w_rate1,
                                               const float* __restrict__ w_alpha,
                                               float* __restrict__ Pt0, float* __restrict__ Pt1,
                                               float* __restrict__ Pt2, int* __restrict__ gcur) {
    __shared__ float V0[128], V1[128], V2[128];
    __shared__ float Q0[128], Q1[128], Q2[128];
    int t = threadIdx.x;
    if (t < KB) gcur[t] = 0;
    int r = t >> 3, seg = t & 7;
    {   // V0 = rowsum(w_rate0)
        const float* p = w_rate0 + r * 128 + seg * 16;
        float s = 0.f;
        #pragma unroll
        for (int k = 0; k < 16; ++k) s += p[k];
        s += __shfl_down(s, 4, 8); s += __shfl_down(s, 2, 8); s += __shfl_down(s, 1, 8);
        if (seg == 0) V0[r] = s;
    }
    if (t < 128) { V1[t] = w_rate1[t]; V2[t] = w_alpha[t]; }
    __syncthreads();
    {   // Q = w_gcn1 @ V
        const float* p = w_gcn1 + r * 128 + seg * 16;
        float q0 = 0.f, q1 = 0.f, q2 = 0.f;
        #pragma unroll
        for (int k = 0; k < 16; ++k) {
            float w = p[k]; int j = seg * 16 + k;
            q0 += w * V0[j]; q1 += w * V1[j]; q2 += w * V2[j];
        }
        q0 += __shfl_down(q0, 4, 8); q0 += __shfl_down(q0, 2, 8); q0 += __shfl_down(q0, 1, 8);
        q1 += __shfl_down(q1, 4, 8); q1 += __shfl_down(q1, 2, 8); q1 += __shfl_down(q1, 1, 8);
        q2 += __shfl_down(q2, 4, 8); q2 += __shfl_down(q2, 2, 8); q2 += __shfl_down(q2, 1, 8);
        if (seg == 0) { Q0[r] = q0; Q1[r] = q1; Q2[r] = q2; }
    }
    __syncthreads();
    {   // P = w_gcn0 @ Q
        const float* p = w_gcn0 + r * 128 + seg * 16;
        float q0 = 0.f, q1 = 0.f, q2 = 0.f;
        #pragma unroll
        for (int k = 0; k < 16; ++k) {
            float w = p[k]; int j = seg * 16 + k;
            q0 += w * Q0[j]; q1 += w * Q1[j]; q2 += w * Q2[j];
        }
        q0 += __shfl_down(q0, 4, 8); q0 += __shfl_down(q0, 2, 8); q0 += __shfl_down(q0, 1, 8);
        q1 += __shfl_down(q1, 4, 8); q1 += __shfl_down(q1, 2, 8); q1 += __shfl_down(q1, 1, 8);
        q2 += __shfl_down(q2, 4, 8); q2 += __shfl_down(q2, 2, 8); q2 += __shfl_down(q2, 1, 8);
        if (seg == 0) { Pt0[r] = q0; Pt1[r] = q1; Pt2[r] = q2; }
    }
}

// ---------------- fused: part (odd role) + raw projection u = h@P (even role) ----------------
// 782 blocks x 512 threads. role = blockIdx&1, id = blockIdx>>1 (0..390).
// part: edges [id*4096, +4096), 8/thread. proj: nodes [id*256, +256), stores u4.xyz ONLY (.w set later by k_cnt).

__global__ __launch_bounds__(512) void k_part_proj(const int* __restrict__ src, const int* __restrict__ dst,
                                                   int* __restrict__ gcur, unsigned int* __restrict__ pk,
                                                   const float* __restrict__ h,
                                                   const float* __restrict__ Pt0, const float* __restrict__ Pt1,
                                                   const float* __restrict__ Pt2,
                                                   float4* __restrict__ u4) {
    __shared__ int cnt[KB];
    __shared__ int base[KB];
    __shared__ float sP0[128], sP1[128], sP2[128];
    int t = threadIdx.x;
    int role = blockIdx.x & 1;
    int id = blockIdx.x >> 1;

    if (role == 0) {
        // ---- partition ----
        if (t < KB) cnt[t] = 0;
        __syncthreads();
        int e0 = id * 4096;
        unsigned int pkv[8];
        int bkt[8];
        #pragma unroll
        for (int i = 0; i < 8; ++i) {
            int e = e0 + i * 512 + t;
            if (e < EE) {
                int s = src[e];
                int d = dst[e];
                int b = s / RR;
                bkt[i] = b;
                pkv[i] = (unsigned int)d | ((unsigned int)(s - b * RR) << 17);
                atomicAdd(&cnt[b], 1);
            } else bkt[i] = -1;
        }
        __syncthreads();
        if (t < KB) base[t] = cnt[t] ? atomicAdd(&gcur[t], cnt[t]) : 0;
        __syncthreads();
        if (t < KB) cnt[t] = 0;
        __syncthreads();
        #pragma unroll
        for (int i = 0; i < 8; ++i) {
            if (bkt[i] >= 0) {
                int rr = atomicAdd(&cnt[bkt[i]], 1);
                int rel = base[bkt[i]] + rr;
                if (rel < CAP) pk[bkt[i] * CAP + rel] = pkv[i];   // overflow guard (stat. impossible)
            }
        }
    } else {
        // ---- raw projection (no nrm) ----
        if (t < 128) { sP0[t] = Pt0[t]; sP1[t] = Pt1[t]; sP2[t] = Pt2[t]; }
        __syncthreads();
        int hw = t >> 5;       // 0..15
        int l32 = t & 31;
        int c4 = l32 * 4;
        float4 c0 = *(const float4*)(sP0 + c4);
        float4 c1 = *(const float4*)(sP1 + c4);
        float4 c2 = *(const float4*)(sP2 + c4);
        int nlo = id * 256;
        for (int i0 = 0; i0 < 256; i0 += 16) {
            int node = nlo + i0 + hw;
            if (node < NN) {
                float4 hv = *(const float4*)(h + (size_t)node * 128 + c4);
                float p0v = hv.x * c0.x + hv.y * c0.y + hv.z * c0.z + hv.w * c0.w;
                float p1v = hv.x * c1.x + hv.y * c1.y + hv.z * c1.z + hv.w * c1.w;
                float p2v = hv.x * c2.x + hv.y * c2.y + hv.z * c2.z + hv.w * c2.w;
                #pragma unroll
                for (int off = 16; off > 0; off >>= 1) {
                    p0v += __shfl_down(p0v, off, 32);
                    p1v += __shfl_down(p1v, off, 32);
                    p2v += __shfl_down(p2v, off, 32);
                }
                if (l32 == 0) {
                    float* up = (float*)&u4[node];
                    *(float2*)up = make_float2(p0v, p1v);   // .xy
                    up[2] = p2v;                            // .z   (.w untouched)
                }
            }
        }
    }
}

// ---------------- cnt: degrees from pk -> nrm[]; stow nrm into u4.w ----------------

__global__ __launch_bounds__(1024) void k_cnt(const unsigned int* __restrict__ pk,
                                              const int* __restrict__ gcur,
                                              float* __restrict__ nrm, float4* __restrict__ u4) {
    __shared__ int c[RR];
    int b = blockIdx.x;
    int t = threadIdx.x;
    int nlo = b * RR;
    int nn = NN - nlo; if (nn > RR) nn = RR;
    if (nn <= 0) return;
    if (t < RR) c[t] = 0;
    __syncthreads();
    const unsigned int* P = pk + b * CAP;
    int m = gcur[b]; if (m > CAP) m = CAP;
    for (int i = t; i < m; i += 1024) atomicAdd(&c[P[i] >> 17], 1);
    __syncthreads();
    if (t < nn) {
        float nv = rsqrtf((float)c[t]);
        nrm[nlo + t] = nv;
        ((float*)&u4[nlo + t])[3] = nv;    // .w only
    }
}

// ---------------- bucketed aggregation; 2-deep pipelined gathers ----------------
// MODE 1: value = T[d].xyz * T[d].w (u4, .w = nrm[d]); store z = nrm^2 * acc
// MODE 2: value = T[d].xyz (z4 pre-scaled);            store p = nrm * acc

template<int MODE>
__global__ __launch_bounds__(1024) void k_agg(const unsigned int* __restrict__ pk,
                                              const int* __restrict__ gcur,
                                              const float4* __restrict__ T, const float* __restrict__ nrm,
                                              float4* __restrict__ outv) {
    __shared__ float s0[RR], s1[RR], s2[RR];
    int b = blockIdx.x;
    int t = threadIdx.x;
    int nlo = b * RR;
    int nn = NN - nlo; if (nn > RR) nn = RR;
    if (nn <= 0) return;
    if (t < RR) { s0[t] = 0.f; s1[t] = 0.f; s2[t] = 0.f; }
    __syncthreads();
    const unsigned int* P = pk + b * CAP;
    int m = gcur[b]; if (m > CAP) m = CAP;
    int i = t;
    for (; i + 1024 < m; i += 2048) {
        unsigned int wa = P[i];
        unsigned int wb = P[i + 1024];
        float4 va = T[wa & 0x1FFFFu];
        float4 vb = T[wb & 0x1FFFFu];
        float ax = va.x, ay = va.y, az = va.z;
        float bx = vb.x, by = vb.y, bz = vb.z;
        if (MODE == 1) { ax *= va.w; ay *= va.w; az *= va.w; bx *= vb.w; by *= vb.w; bz *= vb.w; }
        int ra = (int)(wa >> 17), rb = (int)(wb >> 17);
        atomicAdd(&s0[ra], ax); atomicAdd(&s1[ra], ay); atomicAdd(&s2[ra], az);
        atomicAdd(&s0[rb], bx); atomicAdd(&s1[rb], by); atomicAdd(&s2[rb], bz);
    }
    if (i < m) {
        unsigned int wa = P[i];
        float4 va = T[wa & 0x1FFFFu];
        float ax = va.x, ay = va.y, az = va.z;
        if (MODE == 1) { ax *= va.w; ay *= va.w; az *= va.w; }
        int ra = (int)(wa >> 17);
        atomicAdd(&s0[ra], ax); atomicAdd(&s1[ra], ay); atomicAdd(&s2[ra], az);
    }
    __syncthreads();
    for (int j = t; j < nn; j += 1024) {
        float nv = nrm[nlo + j];
        float sc = (MODE == 1) ? nv * nv : nv;
        outv[nlo + j] = make_float4(sc * s0[j], sc * s1[j], sc * s2[j], 0.f);
    }
}

// ---------------- edge outputs: 4 edges/thread, int4 index loads, float4 output stores ----------------

__global__ __launch_bounds__(256) void k_edge(const int* __restrict__ esrc, const int* __restrict__ edst,
                                              const int* __restrict__ sfake, const int* __restrict__ dfake,
                                              const float4* __restrict__ p4, float* __restrict__ out) {
    int t = threadIdx.x;
    int e0 = blockIdx.x * 1024 + t * 4;
    if (e0 >= EE) return;
    int4 s4  = *(const int4*)(esrc + e0);
    int4 d4  = *(const int4*)(edst + e0);
    int4 sf4 = *(const int4*)(sfake + e0);
    int4 df4 = *(const int4*)(dfake + e0);
    int ss[4] = { s4.x, s4.y, s4.z, s4.w };
    int dd[4] = { d4.x, d4.y, d4.z, d4.w };
    int sf[4] = { sf4.x, sf4.y, sf4.z, sf4.w };
    int df[4] = { df4.x, df4.y, df4.z, df4.w };
    float o0[4], o1[4], o2[4], o3[4], o4[4], o5[4];
    #pragma unroll
    for (int j = 0; j < 4; ++j) {
        int sfj = sf[j]; sfj = sfj < 0 ? 0 : (sfj >= NN ? NN - 1 : sfj);
        int dfj = df[j]; dfj = dfj < 0 ? 0 : (dfj >= NN ? NN - 1 : dfj);
        float4 ps = p4[ss[j]], pd = p4[dd[j]], psf = p4[sfj], pdf = p4[dfj];
        o0[j] = expf(ps.x + pd.x);
        o1[j] = expf(ps.y + pd.y);
        o2[j] = 1.f / (1.f + expf(-(ps.z * pd.z)));
        o3[j] = expf(psf.x + 128.f * pdf.y);
        o4[j] = expf(psf.y + pdf.y);
        o5[j] = 1.f / (1.f + expf(-(ps.z * pdf.z)));
    }
    *(float4*)(out + e0)                  = make_float4(o0[0], o0[1], o0[2], o0[3]);
    *(float4*)(out + (size_t)EE + e0)     = make_float4(o1[0], o1[1], o1[2], o1[3]);
    *(float4*)(out + (size_t)2 * EE + e0) = make_float4(o2[0], o2[1], o2[2], o2[3]);
    *(float4*)(out + (size_t)3 * EE + e0) = make_float4(o3[0], o3[1], o3[2], o3[3]);
    *(float4*)(out + (size_t)4 * EE + e0) = make_float4(o4[0], o4[1], o4[2], o4[3]);
    *(float4*)(out + (size_t)5 * EE + e0) = make_float4(o5[0], o5[1], o5[2], o5[3]);
}

// ---------------- launch ----------------

extern "C" void kernel_launch(void* const* d_in, const int* in_sizes, int n_in,
                              void* d_out, int out_size, void* d_ws, size_t ws_size,
                              hipStream_t stream) {
    const float* h       = (const float*)d_in[0];
    const float* w_gcn0  = (const float*)d_in[1];
    const float* w_gcn1  = (const float*)d_in[2];
    const float* w_rate0 = (const float*)d_in[3];
    const float* w_rate1 = (const float*)d_in[4];
    const float* w_alpha = (const float*)d_in[5];
    const int* edge_src  = (const int*)d_in[6];
    const int* edge_dst  = (const int*)d_in[7];
    const int* src_fake  = (const int*)d_in[8];
    const int* dst_fake  = (const int*)d_in[9];
    float* out = (float*)d_out;

    char* p = (char*)d_ws;
    auto alloc = [&](size_t bytes) {
        char* r = p;
        p += (bytes + 255) & ~(size_t)255;
        return r;
    };
    unsigned int* pk = (unsigned int*)alloc((size_t)KB * CAP * 4);   // 8.4 MB
    int* gcur   = (int*)alloc(KB * 4);
    float* nrm  = (float*)alloc((size_t)NN * 4);
    float4* u4  = (float4*)alloc((size_t)NN * 16);
    float4* z4  = (float4*)alloc((size_t)NN * 16);
    float4* p4  = (float4*)alloc((size_t)NN * 16);
    float* Pt0  = (float*)alloc(512);
    float* Pt1  = (float*)alloc(512);
    float* Pt2  = (float*)alloc(512);

    k_pmat<<<1, 1024, 0, stream>>>(w_gcn0, w_gcn1, w_rate0, w_rate1, w_alpha, Pt0, Pt1, Pt2, gcur);
    k_part_proj<<<782, 512, 0, stream>>>(edge_src, edge_dst, gcur, pk, h, Pt0, Pt1, Pt2, u4);
    k_cnt<<<KB, 1024, 0, stream>>>(pk, gcur, nrm, u4);
    k_agg<1><<<KB, 1024, 0, stream>>>(pk, gcur, u4, nrm, z4);
    k_agg<2><<<KB, 1024, 0, stream>>>(pk, gcur, z4, nrm, p4);
    k_edge<<<(EE + 1023) / 1024, 256, 0, stream>>>(edge_src, edge_dst, src_fake, dst_fake, p4, out);
}